// Round 12
// baseline (175.109 us; speedup 1.0000x reference)
//
#include <hip/hip_runtime.h>

// ---------------------------------------------------------------------------
// EntropyPrunedSelfAttention  (B=4, N=1024, C=768, H=12, hd=64)
// Round 12: ks_fused 32-row blocks — grid (48,32) = 1536 blocks = 6/CU
// (exactly the 26.8KB-LDS cap; was 3/CU at 24% occupancy). Same r10/r11
// single-barrier double-buffered stage shape, wave-per-column-tile, 2 Q
// row-tiles resident, strength-reduced pass 2.
//
// Workspace (byte offsets):
//   xb      bf16[4096*768]      @ 0
//   qwb     bf16[2304*768]      @ 6291456
//   pwb     bf16[768*768]       @ 9830400
//   qb      bf16[48*1024*64]    @ 11010048
//   kb      bf16[48*1024*64]    @ 17301504
//   v       f32 [48*1024*64]    @ 23592960
//   ctxb    bf16[4096*768]      @ 36175872
//   lse     f32 [48*1024]       @ 42467328
//   mask    f32 [1024]          @ 42663936
//   keep    int [1]             @ 42668032
//   colSP   f32 [2048]          @ 42668544   (colS[1024] ++ colP[1024])
// total ~42.7 MB
// ---------------------------------------------------------------------------

typedef __bf16 bf16x8 __attribute__((ext_vector_type(8)));
typedef __bf16 bf16x4 __attribute__((ext_vector_type(4)));
typedef float  f32x4  __attribute__((ext_vector_type(4)));

#define MFMA16(a, b, c) __builtin_amdgcn_mfma_f32_16x16x32_bf16((a), (b), (c), 0, 0, 0)
#define LOG2E_8 0.18033688f  /* 0.125 * log2(e) */

__device__ __forceinline__ void ld_glds16(const __bf16* g, __bf16* s) {
  __builtin_amdgcn_global_load_lds(
      (const __attribute__((address_space(1))) unsigned int*)g,
      (__attribute__((address_space(3))) unsigned int*)s, 16, 0, 0);
}

// --- 1. fp32 -> bf16 conversion + zero colSP/keepCnt -----------------------
__global__ __launch_bounds__(256) void kc_conv(
    const float* __restrict__ x, const float* __restrict__ qw, const float* __restrict__ pw,
    __bf16* __restrict__ xb, __bf16* __restrict__ qwb, __bf16* __restrict__ pwb,
    float* __restrict__ colSP, int* __restrict__ keepCnt)
{
  const int i = blockIdx.x * 256 + threadIdx.x;
  const float4* src;
  __bf16* dst;
  int j;
  if (i < 786432)       { src = (const float4*)x;  dst = xb;  j = i; }
  else if (i < 1228800) { src = (const float4*)qw; dst = qwb; j = i - 786432; }
  else                  { src = (const float4*)pw; dst = pwb; j = i - 1228800; }
  const float4 f = src[j];
  bf16x4 o;
  o[0] = (__bf16)f.x; o[1] = (__bf16)f.y; o[2] = (__bf16)f.z; o[3] = (__bf16)f.w;
  *(bf16x4*)(dst + 4 * (size_t)j) = o;
  if (i < 2048) colSP[i] = 0.f;
  if (i == 0) *keepCnt = 0;
}

// --- 2. QKV GEMM, m97-style: 128x128 tile, async global->LDS staging -------
__global__ __launch_bounds__(256) void kg_qkv(
    const __bf16* __restrict__ A, const __bf16* __restrict__ Bm,
    __bf16* __restrict__ qb, __bf16* __restrict__ kb, float* __restrict__ v)
{
  __shared__ __bf16 As[128 * 64];
  __shared__ __bf16 Bs[128 * 64];
  const int tid = threadIdx.x;
  const int w = tid >> 6, lane = tid & 63, quad = lane >> 4, l = lane & 15;
  const int wm = w >> 1, wn = w & 1;
  const int r0 = blockIdx.y * 128, c0 = blockIdx.x * 128;
  const int srow = lane >> 3, skk = (lane & 7) * 8;

  f32x4 acc[4][4] = {};

  for (int k0 = 0; k0 < 768; k0 += 64) {
    if (k0) __syncthreads();  // previous compute done -> LDS writable
#pragma unroll
    for (int s = 0; s < 4; ++s) {
      const int si = w * 4 + s;               // 0..15
      const int row = si * 8 + srow;
      ld_glds16(A + (size_t)(r0 + row) * 768 + k0 + skk, &As[si * 512]);
      ld_glds16(Bm + (size_t)(c0 + row) * 768 + k0 + skk, &Bs[si * 512]);
    }
    __syncthreads();  // drains vmcnt -> staged tiles visible
#pragma unroll
    for (int kk = 0; kk < 2; ++kk) {
      bf16x8 af[4], bf[4];
#pragma unroll
      for (int t = 0; t < 4; ++t) {
        af[t] = *(const bf16x8*)&As[(wm * 64 + t * 16 + l) * 64 + kk * 32 + quad * 8];
        bf[t] = *(const bf16x8*)&Bs[(wn * 64 + t * 16 + l) * 64 + kk * 32 + quad * 8];
      }
#pragma unroll
      for (int mt = 0; mt < 4; ++mt)
#pragma unroll
        for (int nt = 0; nt < 4; ++nt)
          acc[mt][nt] = MFMA16(af[mt], bf[nt], acc[mt][nt]);
    }
  }

  const int part = c0 / 768;
  const int cbase = c0 % 768;
#pragma unroll
  for (int mt = 0; mt < 4; ++mt) {
#pragma unroll
    for (int nt = 0; nt < 4; ++nt) {
      const int cc = cbase + wn * 64 + nt * 16 + l;  // 0..767
      const int h = cc >> 6, d = cc & 63;
#pragma unroll
      for (int i = 0; i < 4; ++i) {
        const int rg = r0 + wm * 64 + mt * 16 + quad * 4 + i;
        const int b_ = rg >> 10, n = rg & 1023;
        const size_t off = ((size_t)(b_ * 12 + h) * 1024 + n) * 64 + d;
        const float val = acc[mt][nt][i];
        if (part == 0)      qb[off] = (__bf16)val;
        else if (part == 1) kb[off] = (__bf16)val;
        else                v[off]  = val;
      }
    }
  }
}

// --- 3. fused stats v3: 32-row blocks, grid (48,32) ------------------------
// Wave w owns column-tile ct=w; 2 Q row-tiles resident. Double-buffered Ks,
// one barrier per stage: write | barrier | prefetch | compute.
__global__ __launch_bounds__(256) void ks_fused(
    const __bf16* __restrict__ qb, const __bf16* __restrict__ kb,
    float* __restrict__ lse, float* __restrict__ colSP)
{
  __shared__ __bf16 Ks[2][64 * 72];
  __shared__ float sS[1024];
  __shared__ float sP[1024];
  __shared__ float zrow[32];
  const int tid = threadIdx.x;
  const int w = tid >> 6, lane = tid & 63, quad = lane >> 4, l = lane & 15;
  const int bh = blockIdx.x, r0 = blockIdx.y * 32;
  const int row = tid >> 3, ko = (tid & 7) * 8;
  for (int i = tid; i < 1024; i += 256) { sS[i] = 0.f; sP[i] = 0.f; }
  if (tid < 32) zrow[tid] = 0.f;

  // 2 Q row-tiles resident (A-operand: m = l, k = quad*8+j / +32)
  const __bf16* qbase = qb + ((size_t)bh * 1024 + r0 + l) * 64;
  bf16x8 aq0[2], aq1[2];
#pragma unroll
  for (int rt = 0; rt < 2; ++rt) {
    aq0[rt] = *(const bf16x8*)(qbase + rt * 1024 + quad * 8);
    aq1[rt] = *(const bf16x8*)(qbase + rt * 1024 + 32 + quad * 8);
  }
  const __bf16* kbase = kb + (size_t)bh * 65536;  // [1024][64]
  const f32x4 zero = {0.f, 0.f, 0.f, 0.f};
  const int koff = (w * 16 + l) * 72 + quad * 8;

  uint4 ka0 = *(const uint4*)(kbase + (size_t)row * 64 + ko);
  uint4 ka1 = *(const uint4*)(kbase + (size_t)(row + 32) * 64 + ko);

  float z[8] = {};
  // ---- pass 1: row sums of exp ----
  for (int s = 0; s < 16; ++s) {
    __bf16* Kw = Ks[s & 1];
    *(uint4*)&Kw[row * 72 + ko] = ka0;
    *(uint4*)&Kw[(row + 32) * 72 + ko] = ka1;
    __syncthreads();  // chunk s visible; no vmem in flight here
    const int nxt = (s + 1) & 15;  // s==15 prefetches chunk 0 for pass 2
    ka0 = *(const uint4*)(kbase + (size_t)(nxt * 64 + row) * 64 + ko);
    ka1 = *(const uint4*)(kbase + (size_t)(nxt * 64 + row + 32) * 64 + ko);
    const bf16x8 kf0 = *(const bf16x8*)&Kw[koff];
    const bf16x8 kf1 = *(const bf16x8*)&Kw[koff + 32];
#pragma unroll
    for (int rt = 0; rt < 2; ++rt) {
      f32x4 acc = MFMA16(aq0[rt], kf0, zero);
      acc = MFMA16(aq1[rt], kf1, acc);
#pragma unroll
      for (int r = 0; r < 4; ++r) z[rt * 4 + r] += exp2f(acc[r] * LOG2E_8);
    }
  }
#pragma unroll
  for (int off = 1; off < 16; off <<= 1) {
#pragma unroll
    for (int i = 0; i < 8; ++i) z[i] += __shfl_xor(z[i], off);
  }
  if (l == 0) {
#pragma unroll
    for (int rt = 0; rt < 2; ++rt)
#pragma unroll
      for (int r = 0; r < 4; ++r)
        atomicAdd(&zrow[rt * 16 + quad * 4 + r], z[rt * 4 + r]);
  }
  __syncthreads();  // zrow complete
  if (tid < 32) lse[bh * 1024 + r0 + tid] = __logf(zrow[tid]);
  float nlb[8], nlg[8];  // -log2(Z), -ln(Z)
#pragma unroll
  for (int rt = 0; rt < 2; ++rt) {
#pragma unroll
    for (int r = 0; r < 4; ++r) {
      const float Z = zrow[rt * 16 + quad * 4 + r];
      const float lg = __logf(Z);
      nlg[rt * 4 + r] = -lg;
      nlb[rt * 4 + r] = -lg * 1.44269504f;
    }
  }

  // ---- pass 2: column sums of p and p*logp ----
  // p = exp2(fma(a, c, -log2 Z)); logp = fma(a, 0.125, -ln Z); 5 VALU/element.
  for (int s = 0; s < 16; ++s) {
    __bf16* Kw = Ks[s & 1];
    *(uint4*)&Kw[row * 72 + ko] = ka0;
    *(uint4*)&Kw[(row + 32) * 72 + ko] = ka1;
    __syncthreads();
    if (s < 15) {
      ka0 = *(const uint4*)(kbase + (size_t)((s + 1) * 64 + row) * 64 + ko);
      ka1 = *(const uint4*)(kbase + (size_t)((s + 1) * 64 + row + 32) * 64 + ko);
    }
    const bf16x8 kf0 = *(const bf16x8*)&Kw[koff];
    const bf16x8 kf1 = *(const bf16x8*)&Kw[koff + 32];
    float cs = 0.f, cp = 0.f;
#pragma unroll
    for (int rt = 0; rt < 2; ++rt) {
      f32x4 acc = MFMA16(aq0[rt], kf0, zero);
      acc = MFMA16(aq1[rt], kf1, acc);
#pragma unroll
      for (int r = 0; r < 4; ++r) {
        const float a = acc[r];
        const float t = exp2f(fmaf(a, LOG2E_8, nlb[rt * 4 + r]));
        const float d = fmaf(a, 0.125f, nlg[rt * 4 + r]);
        cs += t;
        cp = fmaf(t, d, cp);
      }
    }
    cs += __shfl_xor(cs, 16); cs += __shfl_xor(cs, 32);
    cp += __shfl_xor(cp, 16); cp += __shfl_xor(cp, 32);
    if (lane < 16) {  // wave-private columns: plain LDS accumulate
      sS[s * 64 + w * 16 + l] += cs;
      sP[s * 64 + w * 16 + l] += cp;
    }
  }
  __syncthreads();
  for (int i = tid; i < 1024; i += 256) {
    atomicAdd(&colSP[i], sS[i]);          // 32 row-blocks per address
    atomicAdd(&colSP[1024 + i], sP[i]);
  }
}

// --- 4. entropy -> mask + keepCnt ------------------------------------------
__global__ void k_mask(const float* __restrict__ colSP, const int* __restrict__ cur_epoch,
                       float* __restrict__ mask, int* __restrict__ keepCnt)
{
  const int j = threadIdx.x;
  const float s = colSP[j];
  const float ent = __logf(s) - colSP[1024 + j] / s;
  const int ce = cur_epoch[0];
  float factor = 0.f;
  for (int i = 1; i <= ce; ++i) factor += __expf(-(float)i);
  factor *= 5.0f;
  const float thr = __logf(768.0f) - factor;
  const int keep = (ent <= thr) ? 1 : 0;
  mask[j] = keep ? 1.0f : 0.0f;
  if (keep) atomicAdd(keepCnt, 1);
}

// --- 5. masked AV -> ctxb (bf16). No-op when no column survives. -----------
__global__ __launch_bounds__(256) void k_av(
    const __bf16* __restrict__ qb, const __bf16* __restrict__ kb,
    const float* __restrict__ v, const float* __restrict__ lse,
    const float* __restrict__ mask, const int* __restrict__ keepCnt,
    __bf16* __restrict__ ctxb)
{
  if (*keepCnt == 0) return;  // ctxb unused downstream in this case
  const int tid = threadIdx.x;
  const int bh = blockIdx.x, r0 = blockIdx.y * 32;
  const int b_ = bh / 12, h = bh % 12;
  __shared__ float qs[32][64];
  __shared__ float pbuf[4][8][64];
  for (int i = tid; i < 2048; i += 256)
    qs[i >> 6][i & 63] = (float)qb[((size_t)bh * 1024 + r0) * 64 + i];
  __syncthreads();
  const int w = tid >> 6, l = tid & 63, rb = w * 8;
  float ls[8];
#pragma unroll
  for (int i = 0; i < 8; ++i) ls[i] = lse[bh * 1024 + r0 + rb + i];
  float acc[8] = {};
  for (int chunk = 0; chunk < 16; ++chunk) {
    const float mk = mask[chunk * 64 + l];
    if (__ballot(mk != 0.0f) == 0ull) continue;  // block-uniform
    const __bf16* kp = kb + ((size_t)bh * 1024 + chunk * 64 + l) * 64;
    float s[8] = {};
    for (int d0 = 0; d0 < 64; d0 += 8) {
      const bf16x8 kf = *(const bf16x8*)(kp + d0);
#pragma unroll
      for (int dd = 0; dd < 8; ++dd) {
        const float kv = (float)kf[dd];
#pragma unroll
        for (int i = 0; i < 8; ++i) s[i] += qs[rb + i][d0 + dd] * kv;
      }
    }
    __syncthreads();
#pragma unroll
    for (int i = 0; i < 8; ++i)
      pbuf[w][i][l] = __expf(s[i] * 0.125f - ls[i]) * mk;
    __syncthreads();
    const float* vp = v + ((size_t)bh * 1024 + chunk * 64) * 64 + l;
    for (int jj = 0; jj < 64; ++jj) {
      const float vv = vp[(size_t)jj * 64];
#pragma unroll
      for (int i = 0; i < 8; ++i) acc[i] += pbuf[w][i][jj] * vv;
    }
  }
#pragma unroll
  for (int i = 0; i < 8; ++i)
    ctxb[((size_t)(b_ * 1024 + r0 + rb + i)) * 768 + h * 64 + l] = (__bf16)acc[i];
}

// --- 6. proj GEMM: out = ctxb @ pwb.T + bias; bias-only when keep==0 -------
__global__ __launch_bounds__(256) void kg_proj(
    const __bf16* __restrict__ A, const __bf16* __restrict__ Bm,
    const float* __restrict__ bias, const int* __restrict__ keepCnt,
    float* __restrict__ out)
{
  const int tid = threadIdx.x;
  const int w = tid >> 6, lane = tid & 63, quad = lane >> 4, l = lane & 15;
  const int r0 = blockIdx.y * 64, c0 = blockIdx.x * 64;
  if (*keepCnt == 0) {  // ctx == 0 -> out = bias (uniform branch)
#pragma unroll
    for (int ct = 0; ct < 4; ++ct) {
      const int c = c0 + ct * 16 + l;
      const float bv = bias[c];
#pragma unroll
      for (int i = 0; i < 4; ++i) {
        const int rg = r0 + w * 16 + quad * 4 + i;
        out[(size_t)rg * 768 + c] = bv;
      }
    }
    return;
  }
  __shared__ __bf16 As[64 * 72];
  __shared__ __bf16 Bs[64 * 72];
  const int row = tid >> 3, ko = (tid & 7) * 8;
  const f32x4 zero = {0.f, 0.f, 0.f, 0.f};
  f32x4 acc[4];
#pragma unroll
  for (int ct = 0; ct < 4; ++ct) acc[ct] = zero;

  uint4 a0 = *(const uint4*)(A + (size_t)(r0 + row) * 768 + ko);
  uint4 a1 = *(const uint4*)(A + (size_t)(r0 + row + 32) * 768 + ko);
  uint4 b0 = *(const uint4*)(Bm + (size_t)(c0 + row) * 768 + ko);
  uint4 b1 = *(const uint4*)(Bm + (size_t)(c0 + row + 32) * 768 + ko);

  for (int k0 = 0; k0 < 768; k0 += 64) {
    __syncthreads();
    *(uint4*)&As[row * 72 + ko] = a0;
    *(uint4*)&As[(row + 32) * 72 + ko] = a1;
    *(uint4*)&Bs[row * 72 + ko] = b0;
    *(uint4*)&Bs[(row + 32) * 72 + ko] = b1;
    __syncthreads();
    if (k0 < 704) {
      a0 = *(const uint4*)(A + (size_t)(r0 + row) * 768 + k0 + 64 + ko);
      a1 = *(const uint4*)(A + (size_t)(r0 + row + 32) * 768 + k0 + 64 + ko);
      b0 = *(const uint4*)(Bm + (size_t)(c0 + row) * 768 + k0 + 64 + ko);
      b1 = *(const uint4*)(Bm + (size_t)(c0 + row + 32) * 768 + k0 + 64 + ko);
    }
    const bf16x8 af0 = *(const bf16x8*)&As[(w * 16 + l) * 72 + quad * 8];
    const bf16x8 af1 = *(const bf16x8*)&As[(w * 16 + l) * 72 + 32 + quad * 8];
#pragma unroll
    for (int ct = 0; ct < 4; ++ct) {
      const bf16x8 bf0 = *(const bf16x8*)&Bs[(ct * 16 + l) * 72 + quad * 8];
      const bf16x8 bf1 = *(const bf16x8*)&Bs[(ct * 16 + l) * 72 + 32 + quad * 8];
      acc[ct] = MFMA16(af0, bf0, acc[ct]);
      acc[ct] = MFMA16(af1, bf1, acc[ct]);
    }
  }
#pragma unroll
  for (int ct = 0; ct < 4; ++ct) {
    const int c = c0 + ct * 16 + l;
#pragma unroll
    for (int i = 0; i < 4; ++i) {
      const int rg = r0 + w * 16 + quad * 4 + i;
      out[(size_t)rg * 768 + c] = acc[ct][i] + bias[c];
    }
  }
}

extern "C" void kernel_launch(void* const* d_in, const int* in_sizes, int n_in,
                              void* d_out, int out_size, void* d_ws, size_t ws_size,
                              hipStream_t stream)
{
  const float* x      = (const float*)d_in[0];
  const float* qkv_w  = (const float*)d_in[1];
  const float* proj_w = (const float*)d_in[2];
  const float* proj_b = (const float*)d_in[3];
  const int*   cur_ep = (const int*)d_in[4];

  char* W = (char*)d_ws;
  __bf16* xb    = (__bf16*)(W + 0);
  __bf16* qwb   = (__bf16*)(W + 6291456);
  __bf16* pwb   = (__bf16*)(W + 9830400);
  __bf16* qb    = (__bf16*)(W + 11010048);
  __bf16* kb    = (__bf16*)(W + 17301504);
  float*  v     = (float*) (W + 23592960);
  __bf16* ctxb  = (__bf16*)(W + 36175872);
  float*  lse   = (float*) (W + 42467328);
  float*  mask  = (float*) (W + 42663936);
  int*    keep  = (int*)   (W + 42668032);
  float*  colSP = (float*) (W + 42668544);
  float*  out   = (float*)d_out;

  kc_conv<<<5376, 256, 0, stream>>>(x, qkv_w, proj_w, xb, qwb, pwb, colSP, keep);
  kg_qkv<<<dim3(18, 32), 256, 0, stream>>>(xb, qwb, qb, kb, v);
  ks_fused<<<dim3(48, 32), 256, 0, stream>>>(qb, kb, lse, colSP);
  k_mask<<<1, 1024, 0, stream>>>(colSP, cur_ep, mask, keep);
  k_av<<<dim3(48, 32), 256, 0, stream>>>(qb, kb, v, lse, mask, keep, ctxb);
  kg_proj<<<dim3(12, 64), 256, 0, stream>>>(ctxb, pwb, proj_b, keep, out);
}

// Round 13
// 166.358 us; speedup vs baseline: 1.0526x; 1.0526x over previous
//
#include <hip/hip_runtime.h>

// ---------------------------------------------------------------------------
// EntropyPrunedSelfAttention  (B=4, N=1024, C=768, H=12, hd=64)
// Round 13: r11 geometry (grid 48x16, 4 Q row-tiles, wave-per-column-tile)
// with global_load_lds async K staging into double-buffered UNPADDED
// Ks[2][64*64]. Stage order: barrier | glds(s+1) | compute(s) — the barrier
// drains loads that had the full previous compute phase in flight. Wave w
// stages exactly its own compute rows (buffers wave-private).
//
// Workspace (byte offsets): unchanged from r11 (~42.7 MB).
// ---------------------------------------------------------------------------

typedef __bf16 bf16x8 __attribute__((ext_vector_type(8)));
typedef __bf16 bf16x4 __attribute__((ext_vector_type(4)));
typedef float  f32x4  __attribute__((ext_vector_type(4)));

#define MFMA16(a, b, c) __builtin_amdgcn_mfma_f32_16x16x32_bf16((a), (b), (c), 0, 0, 0)
#define LOG2E_8 0.18033688f  /* 0.125 * log2(e) */

__device__ __forceinline__ void ld_glds16(const __bf16* g, __bf16* s) {
  __builtin_amdgcn_global_load_lds(
      (const __attribute__((address_space(1))) unsigned int*)g,
      (__attribute__((address_space(3))) unsigned int*)s, 16, 0, 0);
}

// --- 1. fp32 -> bf16 conversion + zero colSP/keepCnt -----------------------
__global__ __launch_bounds__(256) void kc_conv(
    const float* __restrict__ x, const float* __restrict__ qw, const float* __restrict__ pw,
    __bf16* __restrict__ xb, __bf16* __restrict__ qwb, __bf16* __restrict__ pwb,
    float* __restrict__ colSP, int* __restrict__ keepCnt)
{
  const int i = blockIdx.x * 256 + threadIdx.x;
  const float4* src;
  __bf16* dst;
  int j;
  if (i < 786432)       { src = (const float4*)x;  dst = xb;  j = i; }
  else if (i < 1228800) { src = (const float4*)qw; dst = qwb; j = i - 786432; }
  else                  { src = (const float4*)pw; dst = pwb; j = i - 1228800; }
  const float4 f = src[j];
  bf16x4 o;
  o[0] = (__bf16)f.x; o[1] = (__bf16)f.y; o[2] = (__bf16)f.z; o[3] = (__bf16)f.w;
  *(bf16x4*)(dst + 4 * (size_t)j) = o;
  if (i < 2048) colSP[i] = 0.f;
  if (i == 0) *keepCnt = 0;
}

// --- 2. QKV GEMM, m97-style: 128x128 tile, async global->LDS staging -------
__global__ __launch_bounds__(256) void kg_qkv(
    const __bf16* __restrict__ A, const __bf16* __restrict__ Bm,
    __bf16* __restrict__ qb, __bf16* __restrict__ kb, float* __restrict__ v)
{
  __shared__ __bf16 As[128 * 64];
  __shared__ __bf16 Bs[128 * 64];
  const int tid = threadIdx.x;
  const int w = tid >> 6, lane = tid & 63, quad = lane >> 4, l = lane & 15;
  const int wm = w >> 1, wn = w & 1;
  const int r0 = blockIdx.y * 128, c0 = blockIdx.x * 128;
  const int srow = lane >> 3, skk = (lane & 7) * 8;

  f32x4 acc[4][4] = {};

  for (int k0 = 0; k0 < 768; k0 += 64) {
    if (k0) __syncthreads();  // previous compute done -> LDS writable
#pragma unroll
    for (int s = 0; s < 4; ++s) {
      const int si = w * 4 + s;               // 0..15
      const int row = si * 8 + srow;
      ld_glds16(A + (size_t)(r0 + row) * 768 + k0 + skk, &As[si * 512]);
      ld_glds16(Bm + (size_t)(c0 + row) * 768 + k0 + skk, &Bs[si * 512]);
    }
    __syncthreads();  // drains vmcnt -> staged tiles visible
#pragma unroll
    for (int kk = 0; kk < 2; ++kk) {
      bf16x8 af[4], bf[4];
#pragma unroll
      for (int t = 0; t < 4; ++t) {
        af[t] = *(const bf16x8*)&As[(wm * 64 + t * 16 + l) * 64 + kk * 32 + quad * 8];
        bf[t] = *(const bf16x8*)&Bs[(wn * 64 + t * 16 + l) * 64 + kk * 32 + quad * 8];
      }
#pragma unroll
      for (int mt = 0; mt < 4; ++mt)
#pragma unroll
        for (int nt = 0; nt < 4; ++nt)
          acc[mt][nt] = MFMA16(af[mt], bf[nt], acc[mt][nt]);
    }
  }

  const int part = c0 / 768;
  const int cbase = c0 % 768;
#pragma unroll
  for (int mt = 0; mt < 4; ++mt) {
#pragma unroll
    for (int nt = 0; nt < 4; ++nt) {
      const int cc = cbase + wn * 64 + nt * 16 + l;  // 0..767
      const int h = cc >> 6, d = cc & 63;
#pragma unroll
      for (int i = 0; i < 4; ++i) {
        const int rg = r0 + wm * 64 + mt * 16 + quad * 4 + i;
        const int b_ = rg >> 10, n = rg & 1023;
        const size_t off = ((size_t)(b_ * 12 + h) * 1024 + n) * 64 + d;
        const float val = acc[mt][nt][i];
        if (part == 0)      qb[off] = (__bf16)val;
        else if (part == 1) kb[off] = (__bf16)val;
        else                v[off]  = val;
      }
    }
  }
}

// --- 3. fused stats v4: r11 shape + glds async staging ---------------------
// grid (48, 16): block = (bh, 64 rows) x 1024 cols. Wave w owns column-tile
// ct=w; 4 Q row-tiles resident. Ks double-buffered UNPADDED [64][64]; wave w
// stages rows w*16..w*16+15 (its own compute rows) via 2 glds-16B/thread.
__global__ __launch_bounds__(256) void ks_fused(
    const __bf16* __restrict__ qb, const __bf16* __restrict__ kb,
    float* __restrict__ lse, float* __restrict__ colSP)
{
  __shared__ __bf16 Ks[2][4096];   // [64][64] per buffer (glds dest: no pad)
  __shared__ float sS[1024];
  __shared__ float sP[1024];
  __shared__ float zrow[64];
  const int tid = threadIdx.x;
  const int w = tid >> 6, lane = tid & 63, quad = lane >> 4, l = lane & 15;
  const int bh = blockIdx.x, r0 = blockIdx.y * 64;
  for (int i = tid; i < 1024; i += 256) { sS[i] = 0.f; sP[i] = 0.f; }
  if (tid < 64) zrow[tid] = 0.f;

  const __bf16* qbase = qb + ((size_t)bh * 1024 + r0 + l) * 64;
  bf16x8 aq0[4], aq1[4];
#pragma unroll
  for (int rt = 0; rt < 4; ++rt) {
    aq0[rt] = *(const bf16x8*)(qbase + rt * 1024 + quad * 8);
    aq1[rt] = *(const bf16x8*)(qbase + rt * 1024 + 32 + quad * 8);
  }
  const __bf16* kbase = kb + (size_t)bh * 65536;  // [1024][64]
  const f32x4 zero = {0.f, 0.f, 0.f, 0.f};
  const int koff = (w * 16 + l) * 64 + quad * 8;
  // staging: wave w covers chunk elements w*1024 .. w*1024+1023
  const __bf16* gsrc = kbase + w * 1024 + lane * 8;

#define STAGE(chunk, buf)                                     \
  do {                                                        \
    const __bf16* g_ = gsrc + (chunk) * 4096;                 \
    ld_glds16(g_,       &Ks[(buf)][w * 1024]);                \
    ld_glds16(g_ + 512, &Ks[(buf)][w * 1024 + 512]);          \
  } while (0)

  STAGE(0, 0);  // prologue

  float z[16] = {};
  // ---- pass 1: row sums of exp ----
  for (int s = 0; s < 16; ++s) {
    __syncthreads();  // drains glds of chunk s (in flight during compute s-1)
    if (s < 15) STAGE(s + 1, (s + 1) & 1);
    else        STAGE(0, 0);  // pass-2 chunk 0 -> buf (16&1)=0; computing buf 1
    const __bf16* Kw = Ks[s & 1];
    const bf16x8 kf0 = *(const bf16x8*)&Kw[koff];
    const bf16x8 kf1 = *(const bf16x8*)&Kw[koff + 32];
#pragma unroll
    for (int rt = 0; rt < 4; ++rt) {
      f32x4 acc = MFMA16(aq0[rt], kf0, zero);
      acc = MFMA16(aq1[rt], kf1, acc);
#pragma unroll
      for (int r = 0; r < 4; ++r) z[rt * 4 + r] += exp2f(acc[r] * LOG2E_8);
    }
  }
#pragma unroll
  for (int off = 1; off < 16; off <<= 1) {
#pragma unroll
    for (int i = 0; i < 16; ++i) z[i] += __shfl_xor(z[i], off);
  }
  if (l == 0) {
#pragma unroll
    for (int rt = 0; rt < 4; ++rt)
#pragma unroll
      for (int r = 0; r < 4; ++r)
        atomicAdd(&zrow[rt * 16 + quad * 4 + r], z[rt * 4 + r]);
  }
  __syncthreads();  // zrow complete (also drains pass-2 chunk-0 staging)
  if (tid < 64) lse[bh * 1024 + r0 + tid] = __logf(zrow[tid]);
  float nlb[16], nlg[16];  // -log2(Z), -ln(Z)
#pragma unroll
  for (int rt = 0; rt < 4; ++rt) {
#pragma unroll
    for (int r = 0; r < 4; ++r) {
      const float Z = zrow[rt * 16 + quad * 4 + r];
      const float lg = __logf(Z);
      nlg[rt * 4 + r] = -lg;
      nlb[rt * 4 + r] = -lg * 1.44269504f;
    }
  }

  // ---- pass 2: column sums of p and p*logp ----
  for (int s = 0; s < 16; ++s) {
    __syncthreads();
    if (s < 15) STAGE(s + 1, (s + 1) & 1);
    const __bf16* Kw = Ks[s & 1];
    const bf16x8 kf0 = *(const bf16x8*)&Kw[koff];
    const bf16x8 kf1 = *(const bf16x8*)&Kw[koff + 32];
    float cs = 0.f, cp = 0.f;
#pragma unroll
    for (int rt = 0; rt < 4; ++rt) {
      f32x4 acc = MFMA16(aq0[rt], kf0, zero);
      acc = MFMA16(aq1[rt], kf1, acc);
#pragma unroll
      for (int r = 0; r < 4; ++r) {
        const float a = acc[r];
        const float t = exp2f(fmaf(a, LOG2E_8, nlb[rt * 4 + r]));
        const float d = fmaf(a, 0.125f, nlg[rt * 4 + r]);
        cs += t;
        cp = fmaf(t, d, cp);
      }
    }
    cs += __shfl_xor(cs, 16); cs += __shfl_xor(cs, 32);
    cp += __shfl_xor(cp, 16); cp += __shfl_xor(cp, 32);
    if (lane < 16) {  // wave-private columns: plain LDS accumulate
      sS[s * 64 + w * 16 + l] += cs;
      sP[s * 64 + w * 16 + l] += cp;
    }
  }
#undef STAGE
  __syncthreads();
  for (int i = tid; i < 1024; i += 256) {
    atomicAdd(&colSP[i], sS[i]);
    atomicAdd(&colSP[1024 + i], sP[i]);
  }
}

// --- 4. entropy -> mask + keepCnt ------------------------------------------
__global__ void k_mask(const float* __restrict__ colSP, const int* __restrict__ cur_epoch,
                       float* __restrict__ mask, int* __restrict__ keepCnt)
{
  const int j = threadIdx.x;
  const float s = colSP[j];
  const float ent = __logf(s) - colSP[1024 + j] / s;
  const int ce = cur_epoch[0];
  float factor = 0.f;
  for (int i = 1; i <= ce; ++i) factor += __expf(-(float)i);
  factor *= 5.0f;
  const float thr = __logf(768.0f) - factor;
  const int keep = (ent <= thr) ? 1 : 0;
  mask[j] = keep ? 1.0f : 0.0f;
  if (keep) atomicAdd(keepCnt, 1);
}

// --- 5. masked AV -> ctxb (bf16). No-op when no column survives. -----------
__global__ __launch_bounds__(256) void k_av(
    const __bf16* __restrict__ qb, const __bf16* __restrict__ kb,
    const float* __restrict__ v, const float* __restrict__ lse,
    const float* __restrict__ mask, const int* __restrict__ keepCnt,
    __bf16* __restrict__ ctxb)
{
  if (*keepCnt == 0) return;  // ctxb unused downstream in this case
  const int tid = threadIdx.x;
  const int bh = blockIdx.x, r0 = blockIdx.y * 32;
  const int b_ = bh / 12, h = bh % 12;
  __shared__ float qs[32][64];
  __shared__ float pbuf[4][8][64];
  for (int i = tid; i < 2048; i += 256)
    qs[i >> 6][i & 63] = (float)qb[((size_t)bh * 1024 + r0) * 64 + i];
  __syncthreads();
  const int w = tid >> 6, l = tid & 63, rb = w * 8;
  float ls[8];
#pragma unroll
  for (int i = 0; i < 8; ++i) ls[i] = lse[bh * 1024 + r0 + rb + i];
  float acc[8] = {};
  for (int chunk = 0; chunk < 16; ++chunk) {
    const float mk = mask[chunk * 64 + l];
    if (__ballot(mk != 0.0f) == 0ull) continue;  // block-uniform
    const __bf16* kp = kb + ((size_t)bh * 1024 + chunk * 64 + l) * 64;
    float s[8] = {};
    for (int d0 = 0; d0 < 64; d0 += 8) {
      const bf16x8 kf = *(const bf16x8*)(kp + d0);
#pragma unroll
      for (int dd = 0; dd < 8; ++dd) {
        const float kv = (float)kf[dd];
#pragma unroll
        for (int i = 0; i < 8; ++i) s[i] += qs[rb + i][d0 + dd] * kv;
      }
    }
    __syncthreads();
#pragma unroll
    for (int i = 0; i < 8; ++i)
      pbuf[w][i][l] = __expf(s[i] * 0.125f - ls[i]) * mk;
    __syncthreads();
    const float* vp = v + ((size_t)bh * 1024 + chunk * 64) * 64 + l;
    for (int jj = 0; jj < 64; ++jj) {
      const float vv = vp[(size_t)jj * 64];
#pragma unroll
      for (int i = 0; i < 8; ++i) acc[i] += pbuf[w][i][jj] * vv;
    }
  }
#pragma unroll
  for (int i = 0; i < 8; ++i)
    ctxb[((size_t)(b_ * 1024 + r0 + rb + i)) * 768 + h * 64 + l] = (__bf16)acc[i];
}

// --- 6. proj GEMM: out = ctxb @ pwb.T + bias; bias-only when keep==0 -------
__global__ __launch_bounds__(256) void kg_proj(
    const __bf16* __restrict__ A, const __bf16* __restrict__ Bm,
    const float* __restrict__ bias, const int* __restrict__ keepCnt,
    float* __restrict__ out)
{
  const int tid = threadIdx.x;
  const int w = tid >> 6, lane = tid & 63, quad = lane >> 4, l = lane & 15;
  const int r0 = blockIdx.y * 64, c0 = blockIdx.x * 64;
  if (*keepCnt == 0) {  // ctx == 0 -> out = bias (uniform branch)
#pragma unroll
    for (int ct = 0; ct < 4; ++ct) {
      const int c = c0 + ct * 16 + l;
      const float bv = bias[c];
#pragma unroll
      for (int i = 0; i < 4; ++i) {
        const int rg = r0 + w * 16 + quad * 4 + i;
        out[(size_t)rg * 768 + c] = bv;
      }
    }
    return;
  }
  __shared__ __bf16 As[64 * 72];
  __shared__ __bf16 Bs[64 * 72];
  const int row = tid >> 3, ko = (tid & 7) * 8;
  const f32x4 zero = {0.f, 0.f, 0.f, 0.f};
  f32x4 acc[4];
#pragma unroll
  for (int ct = 0; ct < 4; ++ct) acc[ct] = zero;

  uint4 a0 = *(const uint4*)(A + (size_t)(r0 + row) * 768 + ko);
  uint4 a1 = *(const uint4*)(A + (size_t)(r0 + row + 32) * 768 + ko);
  uint4 b0 = *(const uint4*)(Bm + (size_t)(c0 + row) * 768 + ko);
  uint4 b1 = *(const uint4*)(Bm + (size_t)(c0 + row + 32) * 768 + ko);

  for (int k0 = 0; k0 < 768; k0 += 64) {
    __syncthreads();
    *(uint4*)&As[row * 72 + ko] = a0;
    *(uint4*)&As[(row + 32) * 72 + ko] = a1;
    *(uint4*)&Bs[row * 72 + ko] = b0;
    *(uint4*)&Bs[(row + 32) * 72 + ko] = b1;
    __syncthreads();
    if (k0 < 704) {
      a0 = *(const uint4*)(A + (size_t)(r0 + row) * 768 + k0 + 64 + ko);
      a1 = *(const uint4*)(A + (size_t)(r0 + row + 32) * 768 + k0 + 64 + ko);
      b0 = *(const uint4*)(Bm + (size_t)(c0 + row) * 768 + k0 + 64 + ko);
      b1 = *(const uint4*)(Bm + (size_t)(c0 + row + 32) * 768 + k0 + 64 + ko);
    }
    const bf16x8 af0 = *(const bf16x8*)&As[(w * 16 + l) * 72 + quad * 8];
    const bf16x8 af1 = *(const bf16x8*)&As[(w * 16 + l) * 72 + 32 + quad * 8];
#pragma unroll
    for (int ct = 0; ct < 4; ++ct) {
      const bf16x8 bf0 = *(const bf16x8*)&Bs[(ct * 16 + l) * 72 + quad * 8];
      const bf16x8 bf1 = *(const bf16x8*)&Bs[(ct * 16 + l) * 72 + 32 + quad * 8];
      acc[ct] = MFMA16(af0, bf0, acc[ct]);
      acc[ct] = MFMA16(af1, bf1, acc[ct]);
    }
  }
#pragma unroll
  for (int ct = 0; ct < 4; ++ct) {
    const int c = c0 + ct * 16 + l;
#pragma unroll
    for (int i = 0; i < 4; ++i) {
      const int rg = r0 + w * 16 + quad * 4 + i;
      out[(size_t)rg * 768 + c] = acc[ct][i] + bias[c];
    }
  }
}

extern "C" void kernel_launch(void* const* d_in, const int* in_sizes, int n_in,
                              void* d_out, int out_size, void* d_ws, size_t ws_size,
                              hipStream_t stream)
{
  const float* x      = (const float*)d_in[0];
  const float* qkv_w  = (const float*)d_in[1];
  const float* proj_w = (const float*)d_in[2];
  const float* proj_b = (const float*)d_in[3];
  const int*   cur_ep = (const int*)d_in[4];

  char* W = (char*)d_ws;
  __bf16* xb    = (__bf16*)(W + 0);
  __bf16* qwb   = (__bf16*)(W + 6291456);
  __bf16* pwb   = (__bf16*)(W + 9830400);
  __bf16* qb    = (__bf16*)(W + 11010048);
  __bf16* kb    = (__bf16*)(W + 17301504);
  float*  v     = (float*) (W + 23592960);
  __bf16* ctxb  = (__bf16*)(W + 36175872);
  float*  lse   = (float*) (W + 42467328);
  float*  mask  = (float*) (W + 42663936);
  int*    keep  = (int*)   (W + 42668032);
  float*  colSP = (float*) (W + 42668544);
  float*  out   = (float*)d_out;

  kc_conv<<<5376, 256, 0, stream>>>(x, qkv_w, proj_w, xb, qwb, pwb, colSP, keep);
  kg_qkv<<<dim3(18, 32), 256, 0, stream>>>(xb, qwb, qb, kb, v);
  ks_fused<<<dim3(48, 16), 256, 0, stream>>>(qb, kb, lse, colSP);
  k_mask<<<1, 1024, 0, stream>>>(colSP, cur_ep, mask, keep);
  k_av<<<dim3(48, 32), 256, 0, stream>>>(qb, kb, v, lse, mask, keep, ctxb);
  kg_proj<<<dim3(12, 64), 256, 0, stream>>>(ctxb, pwb, proj_b, keep, out);
}

// Round 14
// 162.775 us; speedup vs baseline: 1.0758x; 1.0220x over previous
//
#include <hip/hip_runtime.h>

// ---------------------------------------------------------------------------
// EntropyPrunedSelfAttention  (B=4, N=1024, C=768, H=12, hd=64)
// Round 14: ks_fused reverted to r11 exact (best: 52.6us). kg_qkv rewritten
// with the r10 single-barrier double-buffer scheme at 64x64 tiles:
// grid 36x64 = 2304 blocks (9/CU; 4 co-resident at 36.9KB LDS), stage order
// [ds_write(s) | barrier | load(s+1) | compute(s)] — prefetch loads span the
// whole compute phase; padded-72 LDS (conflict-free fragment reads).
//
// Workspace (byte offsets): unchanged (~42.7 MB).
// ---------------------------------------------------------------------------

typedef __bf16 bf16x8 __attribute__((ext_vector_type(8)));
typedef __bf16 bf16x4 __attribute__((ext_vector_type(4)));
typedef float  f32x4  __attribute__((ext_vector_type(4)));

#define MFMA16(a, b, c) __builtin_amdgcn_mfma_f32_16x16x32_bf16((a), (b), (c), 0, 0, 0)
#define LOG2E_8 0.18033688f  /* 0.125 * log2(e) */

// --- 1. fp32 -> bf16 conversion + zero colSP/keepCnt -----------------------
__global__ __launch_bounds__(256) void kc_conv(
    const float* __restrict__ x, const float* __restrict__ qw, const float* __restrict__ pw,
    __bf16* __restrict__ xb, __bf16* __restrict__ qwb, __bf16* __restrict__ pwb,
    float* __restrict__ colSP, int* __restrict__ keepCnt)
{
  const int i = blockIdx.x * 256 + threadIdx.x;
  const float4* src;
  __bf16* dst;
  int j;
  if (i < 786432)       { src = (const float4*)x;  dst = xb;  j = i; }
  else if (i < 1228800) { src = (const float4*)qw; dst = qwb; j = i - 786432; }
  else                  { src = (const float4*)pw; dst = pwb; j = i - 1228800; }
  const float4 f = src[j];
  bf16x4 o;
  o[0] = (__bf16)f.x; o[1] = (__bf16)f.y; o[2] = (__bf16)f.z; o[3] = (__bf16)f.w;
  *(bf16x4*)(dst + 4 * (size_t)j) = o;
  if (i < 2048) colSP[i] = 0.f;
  if (i == 0) *keepCnt = 0;
}

// --- 2. QKV GEMM v3: 64x64 tiles, single-barrier double-buffered stages ----
// grid (36, 64) = 2304 blocks. Stage: write s | barrier | load s+1 | compute s.
__global__ __launch_bounds__(256) void kg_qkv(
    const __bf16* __restrict__ A, const __bf16* __restrict__ Bm,
    __bf16* __restrict__ qb, __bf16* __restrict__ kb, float* __restrict__ v)
{
  __shared__ __bf16 As[2][64 * 72];
  __shared__ __bf16 Bs[2][64 * 72];
  const int tid = threadIdx.x;
  const int w = tid >> 6, lane = tid & 63, quad = lane >> 4, l = lane & 15;
  const int r0 = blockIdx.y * 64, c0 = blockIdx.x * 64;
  const int row = tid >> 3, ko = (tid & 7) * 8;
  const f32x4 zero = {0.f, 0.f, 0.f, 0.f};
  f32x4 acc[4];
#pragma unroll
  for (int ct = 0; ct < 4; ++ct) acc[ct] = zero;

  uint4 a0 = *(const uint4*)(A + (size_t)(r0 + row) * 768 + ko);
  uint4 a1 = *(const uint4*)(A + (size_t)(r0 + row + 32) * 768 + ko);
  uint4 b0 = *(const uint4*)(Bm + (size_t)(c0 + row) * 768 + ko);
  uint4 b1 = *(const uint4*)(Bm + (size_t)(c0 + row + 32) * 768 + ko);

  for (int k0 = 0; k0 < 768; k0 += 64) {
    const int buf = (k0 >> 6) & 1;
    *(uint4*)&As[buf][row * 72 + ko] = a0;
    *(uint4*)&As[buf][(row + 32) * 72 + ko] = a1;
    *(uint4*)&Bs[buf][row * 72 + ko] = b0;
    *(uint4*)&Bs[buf][(row + 32) * 72 + ko] = b1;
    __syncthreads();  // stage s visible; stage s+1 loads not yet issued
    if (k0 < 704) {
      a0 = *(const uint4*)(A + (size_t)(r0 + row) * 768 + k0 + 64 + ko);
      a1 = *(const uint4*)(A + (size_t)(r0 + row + 32) * 768 + k0 + 64 + ko);
      b0 = *(const uint4*)(Bm + (size_t)(c0 + row) * 768 + k0 + 64 + ko);
      b1 = *(const uint4*)(Bm + (size_t)(c0 + row + 32) * 768 + k0 + 64 + ko);
    }
    const bf16x8 af0 = *(const bf16x8*)&As[buf][(w * 16 + l) * 72 + quad * 8];
    const bf16x8 af1 = *(const bf16x8*)&As[buf][(w * 16 + l) * 72 + 32 + quad * 8];
#pragma unroll
    for (int ct = 0; ct < 4; ++ct) {
      const bf16x8 bf0 = *(const bf16x8*)&Bs[buf][(ct * 16 + l) * 72 + quad * 8];
      const bf16x8 bf1 = *(const bf16x8*)&Bs[buf][(ct * 16 + l) * 72 + 32 + quad * 8];
      acc[ct] = MFMA16(af0, bf0, acc[ct]);
      acc[ct] = MFMA16(af1, bf1, acc[ct]);
    }
  }
  const int part = c0 / 768;
  const int h = (c0 % 768) >> 6;
#pragma unroll
  for (int ct = 0; ct < 4; ++ct) {
    const int d = ct * 16 + l;
#pragma unroll
    for (int i = 0; i < 4; ++i) {
      const int rg = r0 + w * 16 + quad * 4 + i;
      const int b_ = rg >> 10, n = rg & 1023;
      const size_t off = ((size_t)(b_ * 12 + h) * 1024 + n) * 64 + d;
      const float val = acc[ct][i];
      if (part == 0)      qb[off] = (__bf16)val;
      else if (part == 1) kb[off] = (__bf16)val;
      else                v[off]  = val;
    }
  }
}

// --- 3. fused stats (r11 exact — best measured: 52.6us) --------------------
// grid (48, 16): wave w owns column-tile ct=w; 4 Q row-tiles resident.
// Double-buffered padded Ks, one barrier per stage.
__global__ __launch_bounds__(256) void ks_fused(
    const __bf16* __restrict__ qb, const __bf16* __restrict__ kb,
    float* __restrict__ lse, float* __restrict__ colSP)
{
  __shared__ __bf16 Ks[2][64 * 72];
  __shared__ float sS[1024];
  __shared__ float sP[1024];
  __shared__ float zrow[64];
  const int tid = threadIdx.x;
  const int w = tid >> 6, lane = tid & 63, quad = lane >> 4, l = lane & 15;
  const int bh = blockIdx.x, r0 = blockIdx.y * 64;
  const int row = tid >> 3, ko = (tid & 7) * 8;
  for (int i = tid; i < 1024; i += 256) { sS[i] = 0.f; sP[i] = 0.f; }
  if (tid < 64) zrow[tid] = 0.f;

  const __bf16* qbase = qb + ((size_t)bh * 1024 + r0 + l) * 64;
  bf16x8 aq0[4], aq1[4];
#pragma unroll
  for (int rt = 0; rt < 4; ++rt) {
    aq0[rt] = *(const bf16x8*)(qbase + rt * 1024 + quad * 8);
    aq1[rt] = *(const bf16x8*)(qbase + rt * 1024 + 32 + quad * 8);
  }
  const __bf16* kbase = kb + (size_t)bh * 65536;  // [1024][64]
  const f32x4 zero = {0.f, 0.f, 0.f, 0.f};
  const int koff = (w * 16 + l) * 72 + quad * 8;

  uint4 ka0 = *(const uint4*)(kbase + (size_t)row * 64 + ko);
  uint4 ka1 = *(const uint4*)(kbase + (size_t)(row + 32) * 64 + ko);

  float z[16] = {};
  // ---- pass 1: row sums of exp ----
  for (int s = 0; s < 16; ++s) {
    __bf16* Kw = Ks[s & 1];
    *(uint4*)&Kw[row * 72 + ko] = ka0;
    *(uint4*)&Kw[(row + 32) * 72 + ko] = ka1;
    __syncthreads();  // chunk s visible; no vmem in flight here
    const int nxt = (s + 1) & 15;  // s==15 prefetches chunk 0 for pass 2
    ka0 = *(const uint4*)(kbase + (size_t)(nxt * 64 + row) * 64 + ko);
    ka1 = *(const uint4*)(kbase + (size_t)(nxt * 64 + row + 32) * 64 + ko);
    const bf16x8 kf0 = *(const bf16x8*)&Kw[koff];
    const bf16x8 kf1 = *(const bf16x8*)&Kw[koff + 32];
#pragma unroll
    for (int rt = 0; rt < 4; ++rt) {
      f32x4 acc = MFMA16(aq0[rt], kf0, zero);
      acc = MFMA16(aq1[rt], kf1, acc);
#pragma unroll
      for (int r = 0; r < 4; ++r) z[rt * 4 + r] += exp2f(acc[r] * LOG2E_8);
    }
  }
#pragma unroll
  for (int off = 1; off < 16; off <<= 1) {
#pragma unroll
    for (int i = 0; i < 16; ++i) z[i] += __shfl_xor(z[i], off);
  }
  if (l == 0) {
#pragma unroll
    for (int rt = 0; rt < 4; ++rt)
#pragma unroll
      for (int r = 0; r < 4; ++r)
        atomicAdd(&zrow[rt * 16 + quad * 4 + r], z[rt * 4 + r]);
  }
  __syncthreads();  // zrow complete
  if (tid < 64) lse[bh * 1024 + r0 + tid] = __logf(zrow[tid]);
  float nlb[16], nlg[16];  // -log2(Z), -ln(Z)
#pragma unroll
  for (int rt = 0; rt < 4; ++rt) {
#pragma unroll
    for (int r = 0; r < 4; ++r) {
      const float Z = zrow[rt * 16 + quad * 4 + r];
      const float lg = __logf(Z);
      nlg[rt * 4 + r] = -lg;
      nlb[rt * 4 + r] = -lg * 1.44269504f;
    }
  }

  // ---- pass 2: column sums of p and p*logp ----
  // p = exp2(fma(a, c, -log2 Z)); logp = fma(a, 0.125, -ln Z); 5 VALU/element.
  for (int s = 0; s < 16; ++s) {
    __bf16* Kw = Ks[s & 1];
    *(uint4*)&Kw[row * 72 + ko] = ka0;
    *(uint4*)&Kw[(row + 32) * 72 + ko] = ka1;
    __syncthreads();
    if (s < 15) {
      ka0 = *(const uint4*)(kbase + (size_t)((s + 1) * 64 + row) * 64 + ko);
      ka1 = *(const uint4*)(kbase + (size_t)((s + 1) * 64 + row + 32) * 64 + ko);
    }
    const bf16x8 kf0 = *(const bf16x8*)&Kw[koff];
    const bf16x8 kf1 = *(const bf16x8*)&Kw[koff + 32];
    float cs = 0.f, cp = 0.f;
#pragma unroll
    for (int rt = 0; rt < 4; ++rt) {
      f32x4 acc = MFMA16(aq0[rt], kf0, zero);
      acc = MFMA16(aq1[rt], kf1, acc);
#pragma unroll
      for (int r = 0; r < 4; ++r) {
        const float a = acc[r];
        const float t = exp2f(fmaf(a, LOG2E_8, nlb[rt * 4 + r]));
        const float d = fmaf(a, 0.125f, nlg[rt * 4 + r]);
        cs += t;
        cp = fmaf(t, d, cp);
      }
    }
    cs += __shfl_xor(cs, 16); cs += __shfl_xor(cs, 32);
    cp += __shfl_xor(cp, 16); cp += __shfl_xor(cp, 32);
    if (lane < 16) {  // wave-private columns: plain LDS accumulate
      sS[s * 64 + w * 16 + l] += cs;
      sP[s * 64 + w * 16 + l] += cp;
    }
  }
  __syncthreads();
  for (int i = tid; i < 1024; i += 256) {
    atomicAdd(&colSP[i], sS[i]);
    atomicAdd(&colSP[1024 + i], sP[i]);
  }
}

// --- 4. entropy -> mask + keepCnt ------------------------------------------
__global__ void k_mask(const float* __restrict__ colSP, const int* __restrict__ cur_epoch,
                       float* __restrict__ mask, int* __restrict__ keepCnt)
{
  const int j = threadIdx.x;
  const float s = colSP[j];
  const float ent = __logf(s) - colSP[1024 + j] / s;
  const int ce = cur_epoch[0];
  float factor = 0.f;
  for (int i = 1; i <= ce; ++i) factor += __expf(-(float)i);
  factor *= 5.0f;
  const float thr = __logf(768.0f) - factor;
  const int keep = (ent <= thr) ? 1 : 0;
  mask[j] = keep ? 1.0f : 0.0f;
  if (keep) atomicAdd(keepCnt, 1);
}

// --- 5. masked AV -> ctxb (bf16). No-op when no column survives. -----------
__global__ __launch_bounds__(256) void k_av(
    const __bf16* __restrict__ qb, const __bf16* __restrict__ kb,
    const float* __restrict__ v, const float* __restrict__ lse,
    const float* __restrict__ mask, const int* __restrict__ keepCnt,
    __bf16* __restrict__ ctxb)
{
  if (*keepCnt == 0) return;  // ctxb unused downstream in this case
  const int tid = threadIdx.x;
  const int bh = blockIdx.x, r0 = blockIdx.y * 32;
  const int b_ = bh / 12, h = bh % 12;
  __shared__ float qs[32][64];
  __shared__ float pbuf[4][8][64];
  for (int i = tid; i < 2048; i += 256)
    qs[i >> 6][i & 63] = (float)qb[((size_t)bh * 1024 + r0) * 64 + i];
  __syncthreads();
  const int w = tid >> 6, l = tid & 63, rb = w * 8;
  float ls[8];
#pragma unroll
  for (int i = 0; i < 8; ++i) ls[i] = lse[bh * 1024 + r0 + rb + i];
  float acc[8] = {};
  for (int chunk = 0; chunk < 16; ++chunk) {
    const float mk = mask[chunk * 64 + l];
    if (__ballot(mk != 0.0f) == 0ull) continue;  // block-uniform
    const __bf16* kp = kb + ((size_t)bh * 1024 + chunk * 64 + l) * 64;
    float s[8] = {};
    for (int d0 = 0; d0 < 64; d0 += 8) {
      const bf16x8 kf = *(const bf16x8*)(kp + d0);
#pragma unroll
      for (int dd = 0; dd < 8; ++dd) {
        const float kv = (float)kf[dd];
#pragma unroll
        for (int i = 0; i < 8; ++i) s[i] += qs[rb + i][d0 + dd] * kv;
      }
    }
    __syncthreads();
#pragma unroll
    for (int i = 0; i < 8; ++i)
      pbuf[w][i][l] = __expf(s[i] * 0.125f - ls[i]) * mk;
    __syncthreads();
    const float* vp = v + ((size_t)bh * 1024 + chunk * 64) * 64 + l;
    for (int jj = 0; jj < 64; ++jj) {
      const float vv = vp[(size_t)jj * 64];
#pragma unroll
      for (int i = 0; i < 8; ++i) acc[i] += pbuf[w][i][jj] * vv;
    }
  }
#pragma unroll
  for (int i = 0; i < 8; ++i)
    ctxb[((size_t)(b_ * 1024 + r0 + rb + i)) * 768 + h * 64 + l] = (__bf16)acc[i];
}

// --- 6. proj GEMM: out = ctxb @ pwb.T + bias; bias-only when keep==0 -------
__global__ __launch_bounds__(256) void kg_proj(
    const __bf16* __restrict__ A, const __bf16* __restrict__ Bm,
    const float* __restrict__ bias, const int* __restrict__ keepCnt,
    float* __restrict__ out)
{
  const int tid = threadIdx.x;
  const int w = tid >> 6, lane = tid & 63, quad = lane >> 4, l = lane & 15;
  const int r0 = blockIdx.y * 64, c0 = blockIdx.x * 64;
  if (*keepCnt == 0) {  // ctx == 0 -> out = bias (uniform branch)
#pragma unroll
    for (int ct = 0; ct < 4; ++ct) {
      const int c = c0 + ct * 16 + l;
      const float bv = bias[c];
#pragma unroll
      for (int i = 0; i < 4; ++i) {
        const int rg = r0 + w * 16 + quad * 4 + i;
        out[(size_t)rg * 768 + c] = bv;
      }
    }
    return;
  }
  __shared__ __bf16 As[64 * 72];
  __shared__ __bf16 Bs[64 * 72];
  const int row = tid >> 3, ko = (tid & 7) * 8;
  const f32x4 zero = {0.f, 0.f, 0.f, 0.f};
  f32x4 acc[4];
#pragma unroll
  for (int ct = 0; ct < 4; ++ct) acc[ct] = zero;

  uint4 a0 = *(const uint4*)(A + (size_t)(r0 + row) * 768 + ko);
  uint4 a1 = *(const uint4*)(A + (size_t)(r0 + row + 32) * 768 + ko);
  uint4 b0 = *(const uint4*)(Bm + (size_t)(c0 + row) * 768 + ko);
  uint4 b1 = *(const uint4*)(Bm + (size_t)(c0 + row + 32) * 768 + ko);

  for (int k0 = 0; k0 < 768; k0 += 64) {
    __syncthreads();
    *(uint4*)&As[row * 72 + ko] = a0;
    *(uint4*)&As[(row + 32) * 72 + ko] = a1;
    *(uint4*)&Bs[row * 72 + ko] = b0;
    *(uint4*)&Bs[(row + 32) * 72 + ko] = b1;
    __syncthreads();
    if (k0 < 704) {
      a0 = *(const uint4*)(A + (size_t)(r0 + row) * 768 + k0 + 64 + ko);
      a1 = *(const uint4*)(A + (size_t)(r0 + row + 32) * 768 + k0 + 64 + ko);
      b0 = *(const uint4*)(Bm + (size_t)(c0 + row) * 768 + k0 + 64 + ko);
      b1 = *(const uint4*)(Bm + (size_t)(c0 + row + 32) * 768 + k0 + 64 + ko);
    }
    const bf16x8 af0 = *(const bf16x8*)&As[(w * 16 + l) * 72 + quad * 8];
    const bf16x8 af1 = *(const bf16x8*)&As[(w * 16 + l) * 72 + 32 + quad * 8];
#pragma unroll
    for (int ct = 0; ct < 4; ++ct) {
      const bf16x8 bf0 = *(const bf16x8*)&Bs[(ct * 16 + l) * 72 + quad * 8];
      const bf16x8 bf1 = *(const bf16x8*)&Bs[(ct * 16 + l) * 72 + 32 + quad * 8];
      acc[ct] = MFMA16(af0, bf0, acc[ct]);
      acc[ct] = MFMA16(af1, bf1, acc[ct]);
    }
  }
#pragma unroll
  for (int ct = 0; ct < 4; ++ct) {
    const int c = c0 + ct * 16 + l;
#pragma unroll
    for (int i = 0; i < 4; ++i) {
      const int rg = r0 + w * 16 + quad * 4 + i;
      out[(size_t)rg * 768 + c] = acc[ct][i] + bias[c];
    }
  }
}

extern "C" void kernel_launch(void* const* d_in, const int* in_sizes, int n_in,
                              void* d_out, int out_size, void* d_ws, size_t ws_size,
                              hipStream_t stream)
{
  const float* x      = (const float*)d_in[0];
  const float* qkv_w  = (const float*)d_in[1];
  const float* proj_w = (const float*)d_in[2];
  const float* proj_b = (const float*)d_in[3];
  const int*   cur_ep = (const int*)d_in[4];

  char* W = (char*)d_ws;
  __bf16* xb    = (__bf16*)(W + 0);
  __bf16* qwb   = (__bf16*)(W + 6291456);
  __bf16* pwb   = (__bf16*)(W + 9830400);
  __bf16* qb    = (__bf16*)(W + 11010048);
  __bf16* kb    = (__bf16*)(W + 17301504);
  float*  v     = (float*) (W + 23592960);
  __bf16* ctxb  = (__bf16*)(W + 36175872);
  float*  lse   = (float*) (W + 42467328);
  float*  mask  = (float*) (W + 42663936);
  int*    keep  = (int*)   (W + 42668032);
  float*  colSP = (float*) (W + 42668544);
  float*  out   = (float*)d_out;

  kc_conv<<<5376, 256, 0, stream>>>(x, qkv_w, proj_w, xb, qwb, pwb, colSP, keep);
  kg_qkv<<<dim3(36, 64), 256, 0, stream>>>(xb, qwb, qb, kb, v);
  ks_fused<<<dim3(48, 16), 256, 0, stream>>>(qb, kb, lse, colSP);
  k_mask<<<1, 1024, 0, stream>>>(colSP, cur_ep, mask, keep);
  k_av<<<dim3(48, 32), 256, 0, stream>>>(qb, kb, v, lse, mask, keep, ctxb);
  kg_proj<<<dim3(12, 64), 256, 0, stream>>>(ctxb, pwb, proj_b, keep, out);
}